// Round 13
// baseline (167.464 us; speedup 1.0000x reference)
//
#include <hip/hip_runtime.h>

typedef unsigned short ushort_t;
typedef __attribute__((ext_vector_type(8))) short bf16x8;
typedef __attribute__((ext_vector_type(4))) float f32x4;

// Model constants (fixed by the reference)
constexpr int N_   = 512;
constexpr int D_   = 64;
constexpr int H_   = 6;
constexpr int DH_  = 32;
constexpr int CB_  = 16;
constexpr int SB_  = 8;
constexpr int HD_  = H_ * DH_;   // 192
constexpr int CD_  = CB_ * DH_;  // 512
constexpr int nC_  = N_ / CB_;   // 32
constexpr int nF_  = N_ / SB_;   // 64
constexpr float SCALE_ = 0.17677669529663687f; // 32^-0.5
constexpr float NEG_ = -3.4e38f;

__device__ __forceinline__ ushort_t f2bf(float x) {
    unsigned u = __float_as_uint(x);
    unsigned r = u + 0x7FFFu + ((u >> 16) & 1u);   // RNE
    return (ushort_t)(r >> 16);
}

// Fragment-major address for a [rows][512] bf16 matrix consumed by
// mfma_f32_16x16x32_bf16 (wave fragment load = one coalesced 1KB read).
__device__ __forceinline__ size_t frag_addr(int row, int k) {
    return (size_t)(row >> 4) * 8192 + (size_t)(k >> 5) * 512
         + (size_t)((k >> 3) & 3) * 128 + (size_t)(row & 15) * 8 + (k & 7);
}

// ---------------------------------------------------------------------------
// K0: transpose + split Wkc1 / Wvc1 (512x512 f32, [k][j]) -> frag-major bf16
// hi/lo over [j][k]. grid (8,8,2) x 256 threads, 64x64 tiles via LDS.
// ---------------------------------------------------------------------------
__global__ __launch_bounds__(256) void k_cvtW(
    const float* __restrict__ Wk1, const float* __restrict__ Wv1,
    ushort_t* __restrict__ wtk_hi, ushort_t* __restrict__ wtk_lo,
    ushort_t* __restrict__ wtv_hi, ushort_t* __restrict__ wtv_lo)
{
    const float* W = blockIdx.z ? Wv1 : Wk1;
    ushort_t* ohi = blockIdx.z ? wtv_hi : wtk_hi;
    ushort_t* olo = blockIdx.z ? wtv_lo : wtk_lo;
    const int k0 = blockIdx.x * 64, j0 = blockIdx.y * 64;
    const int t = threadIdx.x;
    __shared__ float tile[64][65];
    #pragma unroll 4
    for (int i = 0; i < 16; ++i) {
        const int lin = t + i * 256;
        const int kk = lin >> 6, jj = lin & 63;
        tile[kk][jj] = W[(size_t)(k0 + kk) * 512 + j0 + jj];
    }
    __syncthreads();
    #pragma unroll 4
    for (int i = 0; i < 16; ++i) {
        const int lin = t + i * 256;
        const int jj = lin >> 6, kk = lin & 63;
        const float x = tile[kk][jj];
        const ushort_t h = f2bf(x);
        const float hf = __uint_as_float((unsigned)h << 16);
        const size_t fo = frag_addr(j0 + jj, k0 + kk);
        ohi[fo] = h;
        olo[fo] = f2bf(x - hf);
    }
}

// ---------------------------------------------------------------------------
// K1: embed + norm + Q/K/V/gate projections + RoPE; kin/vin emitted bf16 hi/lo
// in MFMA-fragment-major layout. Block = 64 consecutive n (4 chunk-rows) so
// fragment 64B lines are written densely (no partial-line amplification).
// 768 threads = 12 waves; wave w: m = w>>2, quarter = w&3 -> 16 rows x 64 cols.
// ---------------------------------------------------------------------------
__global__ __launch_bounds__(768) void k_embed(
    const float* __restrict__ x, const float* __restrict__ We, const float* __restrict__ be,
    const float* __restrict__ gamma,
    const float* __restrict__ Wq, const float* __restrict__ Wk, const float* __restrict__ Wv,
    const float* __restrict__ kpos, const float* __restrict__ vpos,
    const float* __restrict__ Wg, const float* __restrict__ bg,
    float* __restrict__ q, float* __restrict__ qr, float* __restrict__ kr,
    float* __restrict__ v,
    ushort_t* __restrict__ kin_hi, ushort_t* __restrict__ kin_lo,
    ushort_t* __restrict__ vin_hi, ushort_t* __restrict__ vin_lo,
    float* __restrict__ g)
{
    const int t  = threadIdx.x;
    const int w  = t >> 6;        // 0..11
    const int ln = t & 63;
    const int m  = w >> 2;        // 0..2 column group
    const int q4 = w & 3;         // 0..3 row quarter
    const int n00 = blockIdx.x * 64;
    const int b = n00 / N_;
    const int nbase0 = n00 % N_;

    __shared__ float hn[64][64];  // 16 KB

    // phase 1: normalized embedding rows (wave-strided over 64 rows)
    for (int r = w; r < 64; r += 12) {
        const int n = nbase0 + r;
        float xv = x[b * N_ + n];
        float h = fmaf(xv, We[ln], be[ln]);
        float ss = h * h;
        #pragma unroll
        for (int off = 32; off; off >>= 1) ss += __shfl_down(ss, off);
        ss = __shfl(ss, 0);
        float sc = 8.0f / fmaxf(sqrtf(ss), 1e-12f);
        hn[r][ln] = h * sc * (gamma[ln] + 1.0f);
    }
    __syncthreads();

    // phase 2: wave computes its 64 output columns for its 16 rows
    const int nbase = nbase0 + q4 * 16;
    const int e  = ln + (m << 6);
    const int hh = e >> 5;
    const int dh = e & 31;
    float aq[16], ak[16], av[16];
    #pragma unroll
    for (int r = 0; r < 16; ++r) { aq[r] = 0.f; ak[r] = 0.f; av[r] = 0.f; }
    #pragma unroll 4
    for (int dd = 0; dd < 64; ++dd) {
        const float wq_ = Wq[dd * HD_ + e];
        const float wk_ = Wk[dd * HD_ + e];
        const float wv_ = Wv[dd * HD_ + e];
        #pragma unroll
        for (int r = 0; r < 16; ++r) {
            const float hv = hn[q4 * 16 + r][dd];
            aq[r] = fmaf(hv, wq_, aq[r]);
            ak[r] = fmaf(hv, wk_, ak[r]);
            av[r] = fmaf(hv, wv_, av[r]);
        }
    }
    const float invf = exp2f((float)(dh & ~1) * -0.41524101186092029f);
    #pragma unroll
    for (int r = 0; r < 16; ++r) {
        const int n = nbase + r;
        const size_t o = ((size_t)(b * H_ + hh) * N_ + n) * DH_ + dh;
        q[o] = aq[r];
        v[o] = av[r];
        const int pix = (hh * CB_ + (n & (CB_ - 1))) * DH_ + dh;
        const float kinv = ak[r] + kpos[pix];
        const float vinv = av[r] + vpos[pix];
        {
            const int row = (b * H_ + hh) * nC_ + (n >> 4);
            const int k   = (n & 15) * 32 + dh;
            const size_t fo = frag_addr(row, k);
            const ushort_t kh = f2bf(kinv);
            kin_hi[fo] = kh;
            kin_lo[fo] = f2bf(kinv - __uint_as_float((unsigned)kh << 16));
            const ushort_t vh = f2bf(vinv);
            vin_hi[fo] = vh;
            vin_lo[fo] = f2bf(vinv - __uint_as_float((unsigned)vh << 16));
        }
        const float aqp = __shfl_xor(aq[r], 1);
        const float akp = __shfl_xor(ak[r], 1);
        float sA, cA;
        __sincosf((float)n * invf, &sA, &cA);
        float rq, rk;
        if (dh & 1) { rq = fmaf(aqp, sA, aq[r] * cA); rk = fmaf(akp, sA, ak[r] * cA); }
        else        { rq = fmaf(-aqp, sA, aq[r] * cA); rk = fmaf(-akp, sA, ak[r] * cA); }
        qr[o] = rq; kr[o] = rk;
    }

    // gate: 18 outputs per row, wave-strided rows
    if (ln < 18) {
        for (int r = w; r < 64; r += 12) {
            const int n = nbase0 + r;
            float a = bg[ln];
            for (int dd = 0; dd < 64; ++dd) a = fmaf(hn[r][dd], Wg[dd * 18 + ln], a);
            const float gv = 1.0f / (1.0f + __expf(-a));
            g[((size_t)(b * H_ + ln / 3) * N_ + n) * 3 + (ln % 3)] = gv;
        }
    }
}

// ---------------------------------------------------------------------------
// K2: compression MLP via bf16x3 MFMA, fragment-major direct loads.
// Also writes the memory-token slot 0 (block == one bh).
// ---------------------------------------------------------------------------
__global__ __launch_bounds__(256) void k_compress(
    const ushort_t* __restrict__ kin_hi, const ushort_t* __restrict__ kin_lo,
    const ushort_t* __restrict__ vin_hi, const ushort_t* __restrict__ vin_lo,
    const ushort_t* __restrict__ wtk_hi, const ushort_t* __restrict__ wtk_lo,
    const ushort_t* __restrict__ wtv_hi, const ushort_t* __restrict__ wtv_lo,
    const float* __restrict__ bk1, const float* __restrict__ Wk2, const float* __restrict__ bk2,
    const float* __restrict__ bv1, const float* __restrict__ Wv2, const float* __restrict__ bv2,
    const float* __restrict__ mk, const float* __restrict__ mv,
    float* __restrict__ ck, float* __restrict__ cv)
{
    const bool isv = blockIdx.y != 0;
    const ushort_t* xhi = isv ? vin_hi : kin_hi;
    const ushort_t* xlo = isv ? vin_lo : kin_lo;
    const ushort_t* whi = isv ? wtv_hi : wtk_hi;
    const ushort_t* wlo = isv ? wtv_lo : wtk_lo;
    const float* b1 = isv ? bv1 : bk1;
    const float* W2 = isv ? Wv2 : Wk2;
    const float* b2 = isv ? bv2 : bk2;
    const float* mtok = isv ? mv : mk;
    float* outp = isv ? cv : ck;

    const int row0 = blockIdx.x * 32;     // block == bh (32 rows = nC)
    const int t = threadIdx.x;
    const int w = t >> 6, l = t & 63;
    const int lrow = l & 15, kg = l >> 4;
    const int n0w = w * 128;

    __shared__ float hid[32 * 512];       // 64 KB
    __shared__ float wred[4 * 16 * 32];   // 8 KB

    // memory token -> slot 0
    if (t < 32) {
        outp[(size_t)blockIdx.x * 33 * DH_ + t] = mtok[(blockIdx.x % H_) * DH_ + t];
    }

    f32x4 acc[2][8];
    #pragma unroll
    for (int nt = 0; nt < 8; ++nt) {
        const float bv_ = b1[n0w + nt * 16 + lrow];
        #pragma unroll
        for (int mt = 0; mt < 2; ++mt) {
            acc[mt][nt][0] = bv_; acc[mt][nt][1] = bv_;
            acc[mt][nt][2] = bv_; acc[mt][nt][3] = bv_;
        }
    }
    const ushort_t* Ah = xhi + (size_t)(row0 >> 4) * 8192;
    const ushort_t* Al = xlo + (size_t)(row0 >> 4) * 8192;
    const ushort_t* Bh = whi + (size_t)(n0w >> 4) * 8192;
    const ushort_t* Bl = wlo + (size_t)(n0w >> 4) * 8192;
    const int lofs = l * 8;

    for (int ks = 0; ks < 16; ++ks) {
        const int kb = ks * 512 + lofs;
        const bf16x8 ah0 = *(const bf16x8*)(Ah + kb);
        const bf16x8 ah1 = *(const bf16x8*)(Ah + 8192 + kb);
        const bf16x8 al0 = *(const bf16x8*)(Al + kb);
        const bf16x8 al1 = *(const bf16x8*)(Al + 8192 + kb);
        #pragma unroll
        for (int nt = 0; nt < 8; ++nt) {
            const bf16x8 bh = *(const bf16x8*)(Bh + nt * 8192 + kb);
            const bf16x8 bl = *(const bf16x8*)(Bl + nt * 8192 + kb);
            acc[0][nt] = __builtin_amdgcn_mfma_f32_16x16x32_bf16(ah0, bh, acc[0][nt], 0, 0, 0);
            acc[0][nt] = __builtin_amdgcn_mfma_f32_16x16x32_bf16(ah0, bl, acc[0][nt], 0, 0, 0);
            acc[0][nt] = __builtin_amdgcn_mfma_f32_16x16x32_bf16(al0, bh, acc[0][nt], 0, 0, 0);
            acc[1][nt] = __builtin_amdgcn_mfma_f32_16x16x32_bf16(ah1, bh, acc[1][nt], 0, 0, 0);
            acc[1][nt] = __builtin_amdgcn_mfma_f32_16x16x32_bf16(ah1, bl, acc[1][nt], 0, 0, 0);
            acc[1][nt] = __builtin_amdgcn_mfma_f32_16x16x32_bf16(al1, bh, acc[1][nt], 0, 0, 0);
        }
    }
    #pragma unroll
    for (int mt = 0; mt < 2; ++mt) {
        #pragma unroll
        for (int nt = 0; nt < 8; ++nt) {
            const int col = n0w + nt * 16 + lrow;
            #pragma unroll
            for (int r = 0; r < 4; ++r) {
                const int row = mt * 16 + kg * 4 + r;
                hid[row * 512 + col] = fmaxf(acc[mt][nt][r], 0.0f);
            }
        }
    }
    __syncthreads();

    const int o = t & 31, seg = t >> 5;
    for (int half = 0; half < 2; ++half) {
        const int r0 = half * 16;
        float s[16];
        #pragma unroll
        for (int r = 0; r < 16; ++r) s[r] = 0.f;
        for (int di = 0; di < 64; ++di) {
            const int dd = seg * 64 + di;
            const float w2 = W2[(size_t)dd * 32 + o];
            #pragma unroll
            for (int r = 0; r < 16; ++r) s[r] = fmaf(hid[(r0 + r) * 512 + dd], w2, s[r]);
        }
        #pragma unroll
        for (int r = 0; r < 16; ++r) s[r] += __shfl_xor(s[r], 32);
        if (l < 32) {
            #pragma unroll
            for (int r = 0; r < 16; ++r) wred[(w * 16 + r) * 32 + o] = s[r];
        }
        __syncthreads();
        {
            const int rr = t >> 5;   // 0..7
            #pragma unroll
            for (int u = 0; u < 2; ++u) {
                const int r = rr + u * 8;
                const float val = wred[r * 32 + o] + wred[(16 + r) * 32 + o]
                                + wred[(32 + r) * 32 + o] + wred[(48 + r) * 32 + o] + b2[o];
                const int grow = row0 + r0 + r;
                outp[((size_t)(grow >> 5) * 33 + 1 + (grow & 31)) * DH_ + o] = val;
            }
        }
        __syncthreads();
    }
}

// ---------------------------------------------------------------------------
// K3: fused attention + pooling partial. Quarter-wave per query; CONSECUTIVE
// n per block (L1 locality); epilogue reduces the block's 64 query outputs
// (mean-pool numerator) -> partial[bh*8+blk][32].
// ---------------------------------------------------------------------------
__global__ __launch_bounds__(256) void k_attn(
    const float* __restrict__ q, const float* __restrict__ qr,
    const float* __restrict__ kr, const float* __restrict__ v,
    const float* __restrict__ ck, const float* __restrict__ cv,
    const float* __restrict__ g, float* __restrict__ partial)
{
    const int t = threadIdx.x;
    const int sub = t & 3;
    const int wv = t >> 6;
    const int l = t & 63;
    const int bh = blockIdx.x >> 3;
    const int blk = blockIdx.x & 7;
    const int qi = t >> 2;                    // 0..63 consecutive
    const int n = blk * 64 + qi;
    const int qb = n >> 3;

    float qv[8];
    {
        const float4* p = (const float4*)(q + ((size_t)bh * N_ + n) * DH_ + sub * 8);
        const float4 f0 = p[0], f1 = p[1];
        qv[0]=f0.x; qv[1]=f0.y; qv[2]=f0.z; qv[3]=f0.w;
        qv[4]=f1.x; qv[5]=f1.y; qv[6]=f1.z; qv[7]=f1.w;
    }
    const float* ckb = ck + (size_t)bh * 33 * DH_;
    const float* cvb = cv + (size_t)bh * 33 * DH_;

    float mx = -INFINITY, den = 0.f;
    float cres[8];
    #pragma unroll
    for (int d = 0; d < 8; ++d) cres[d] = 0.f;
    float m2 = -1000.0f, sum2 = 1.0f;
    float v1 = -INFINITY, v2 = -INFINITY;
    int i1 = 0, i2 = 0;

    const int jend = 1 + max(n >> 4, (qb + 1) >> 1);
    for (int j = 0; j < jend; ++j) {
        float a = 0.f;
        {
            const float4* kp = (const float4*)(ckb + j * DH_ + sub * 8);
            const float4 f0 = kp[0], f1 = kp[1];
            a = fmaf(qv[0], f0.x, a); a = fmaf(qv[1], f0.y, a);
            a = fmaf(qv[2], f0.z, a); a = fmaf(qv[3], f0.w, a);
            a = fmaf(qv[4], f1.x, a); a = fmaf(qv[5], f1.y, a);
            a = fmaf(qv[6], f1.z, a); a = fmaf(qv[7], f1.w, a);
        }
        a += __shfl_xor(a, 1);
        a += __shfl_xor(a, 2);
        const bool ok = (j == 0) || (j * CB_ - 1 < n);
        a = ok ? a * SCALE_ : NEG_;

        float p;
        if (a > mx) {
            const float sc_ = __expf(mx - a);
            den *= sc_;
            #pragma unroll
            for (int d = 0; d < 8; ++d) cres[d] *= sc_;
            mx = a; p = 1.0f;
        } else {
            p = __expf(a - mx);
        }
        den += p;
        {
            const float4* vp = (const float4*)(cvb + j * DH_ + sub * 8);
            const float4 f0 = vp[0], f1 = vp[1];
            cres[0] = fmaf(p, f0.x, cres[0]); cres[1] = fmaf(p, f0.y, cres[1]);
            cres[2] = fmaf(p, f0.z, cres[2]); cres[3] = fmaf(p, f0.w, cres[3]);
            cres[4] = fmaf(p, f1.x, cres[4]); cres[5] = fmaf(p, f1.y, cres[5]);
            cres[6] = fmaf(p, f1.z, cres[6]); cres[7] = fmaf(p, f1.w, cres[7]);
        }

        if (j >= 1) {
            const int f0i = 2 * (j - 1);
            const int cnt = (qb > f0i) + (qb > f0i + 1);
            if (cnt) {
                if (a > m2) {
                    sum2 = fmaf(sum2, __expf(m2 - a), (float)cnt);
                    m2 = a;
                } else {
                    sum2 = fmaf((float)cnt, __expf(a - m2), sum2);
                }
                if (a > v1) {
                    if (cnt == 2) { v2 = a; i2 = f0i + 1; }
                    else          { v2 = v1; i2 = i1; }
                    v1 = a; i1 = f0i;
                } else if (a > v2) {
                    v2 = a; i2 = f0i;
                }
            }
        }
    }
    {
        const float invd = 1.0f / den;
        #pragma unroll
        for (int d = 0; d < 8; ++d) cres[d] *= invd;
    }
    const float isum = 1.0f / sum2;
    const bool bm0 = __expf(v1 - m2) * isum > 1e-10f;
    const bool bm1 = __expf(v2 - m2) * isum > 1e-10f;

    float qrv[8];
    {
        const float4* p = (const float4*)(qr + ((size_t)bh * N_ + n) * DH_ + sub * 8);
        const float4 f0 = p[0], f1 = p[1];
        qrv[0]=f0.x; qrv[1]=f0.y; qrv[2]=f0.z; qrv[3]=f0.w;
        qrv[4]=f1.x; qrv[5]=f1.y; qrv[6]=f1.z; qrv[7]=f1.w;
    }
    const float* krb = kr + (size_t)bh * N_ * DH_;
    const float* vb  = v  + (size_t)bh * N_ * DH_;

    int blocks[3]; bool bmask[3];
    blocks[0] = i1; blocks[1] = i2; blocks[2] = qb;
    bmask[0] = bm0; bmask[1] = bm1; bmask[2] = true;

    float fmx = -INFINITY, fden = 0.f;
    float fo[8];
    #pragma unroll
    for (int d = 0; d < 8; ++d) fo[d] = 0.f;
    #pragma unroll
    for (int s = 0; s < 3; ++s) {
        const int base = blocks[s] * SB_;
        #pragma unroll
        for (int j = 0; j < 8; ++j) {
            const int row = base + j;
            float a = 0.f;
            {
                const float4* kp = (const float4*)(krb + (size_t)row * DH_ + sub * 8);
                const float4 f0 = kp[0], f1 = kp[1];
                a = fmaf(qrv[0], f0.x, a); a = fmaf(qrv[1], f0.y, a);
                a = fmaf(qrv[2], f0.z, a); a = fmaf(qrv[3], f0.w, a);
                a = fmaf(qrv[4], f1.x, a); a = fmaf(qrv[5], f1.y, a);
                a = fmaf(qrv[6], f1.z, a); a = fmaf(qrv[7], f1.w, a);
            }
            a += __shfl_xor(a, 1);
            a += __shfl_xor(a, 2);
            const bool ok = (s < 2) ? bmask[s] : (j <= (n & 7));
            a = ok ? a * SCALE_ : NEG_;

            float p;
            if (a > fmx) {
                const float sc_ = __expf(fmx - a);
                fden *= sc_;
                #pragma unroll
                for (int d = 0; d < 8; ++d) fo[d] *= sc_;
                fmx = a; p = 1.0f;
            } else {
                p = __expf(a - fmx);
            }
            fden += p;
            const float4* vp = (const float4*)(vb + (size_t)row * DH_ + sub * 8);
            const float4 f0 = vp[0], f1 = vp[1];
            fo[0] = fmaf(p, f0.x, fo[0]); fo[1] = fmaf(p, f0.y, fo[1]);
            fo[2] = fmaf(p, f0.z, fo[2]); fo[3] = fmaf(p, f0.w, fo[3]);
            fo[4] = fmaf(p, f1.x, fo[4]); fo[5] = fmaf(p, f1.y, fo[5]);
            fo[6] = fmaf(p, f1.z, fo[6]); fo[7] = fmaf(p, f1.w, fo[7]);
        }
    }
    const float finv = 1.0f / fden;

    float wmx = -INFINITY, wden = 0.f;
    float so[8];
    #pragma unroll
    for (int d = 0; d < 8; ++d) so[d] = 0.f;
    #pragma unroll
    for (int w = 0; w < 8; ++w) {
        const int row = (n - w) >= 0 ? (n - w) : 0;
        float a;
        if (w <= n) {
            a = 0.f;
            const float4* kp = (const float4*)(krb + (size_t)row * DH_ + sub * 8);
            const float4 f0 = kp[0], f1 = kp[1];
            a = fmaf(qrv[0], f0.x, a); a = fmaf(qrv[1], f0.y, a);
            a = fmaf(qrv[2], f0.z, a); a = fmaf(qrv[3], f0.w, a);
            a = fmaf(qrv[4], f1.x, a); a = fmaf(qrv[5], f1.y, a);
            a = fmaf(qrv[6], f1.z, a); a = fmaf(qrv[7], f1.w, a);
            a += __shfl_xor(a, 1);
            a += __shfl_xor(a, 2);
            a *= SCALE_;
        } else a = NEG_;

        float p;
        if (a > wmx) {
            const float sc_ = __expf(wmx - a);
            wden *= sc_;
            #pragma unroll
            for (int d = 0; d < 8; ++d) so[d] *= sc_;
            wmx = a; p = 1.0f;
        } else {
            p = __expf(a - wmx);
        }
        wden += p;
        const float4* vp = (const float4*)(vb + (size_t)row * DH_ + sub * 8);
        const float4 f0 = vp[0], f1 = vp[1];
        so[0] = fmaf(p, f0.x, so[0]); so[1] = fmaf(p, f0.y, so[1]);
        so[2] = fmaf(p, f0.z, so[2]); so[3] = fmaf(p, f0.w, so[3]);
        so[4] = fmaf(p, f1.x, so[4]); so[5] = fmaf(p, f1.y, so[5]);
        so[6] = fmaf(p, f1.z, so[6]); so[7] = fmaf(p, f1.w, so[7]);
    }
    const float winv = 1.0f / wden;

    const float g0 = g[((size_t)bh * N_ + n) * 3];
    const float g1 = g[((size_t)bh * N_ + n) * 3 + 1];
    const float g2 = g[((size_t)bh * N_ + n) * 3 + 2];
    float o[8];
    #pragma unroll
    for (int d = 0; d < 8; ++d)
        o[d] = g0 * cres[d] + g1 * (fo[d] * finv) + g2 * (so[d] * winv);

    // ---- pooling partial: sum this block's 64 queries ----
    #pragma unroll
    for (int d = 0; d < 8; ++d) {
        o[d] += __shfl_down(o[d], 32);
        o[d] += __shfl_down(o[d], 16);
        o[d] += __shfl_down(o[d], 8);
        o[d] += __shfl_down(o[d], 4);
    }
    __shared__ float red[4][32];
    if (l < 4) {
        #pragma unroll
        for (int d = 0; d < 8; ++d) red[wv][l * 8 + d] = o[d];
    }
    __syncthreads();
    if (t < 32) {
        const float s = red[0][t] + red[1][t] + red[2][t] + red[3][t];
        partial[((size_t)bh * 8 + blk) * 32 + t] = s;
    }
}

// ---------------------------------------------------------------------------
// K5: pooled = (sum partials)@Wo/N ; gelu MLP head -> out (B,7)
// partial layout: [bh][8][32]
// ---------------------------------------------------------------------------
__global__ void k_head(const float* __restrict__ partial, const float* __restrict__ Wo,
                       const float* __restrict__ Wh1, const float* __restrict__ bh1,
                       const float* __restrict__ Wh2, const float* __restrict__ bh2,
                       float* __restrict__ out)
{
    const int b = blockIdx.x;
    const int t = threadIdx.x; // 64
    __shared__ float cs[192];
    __shared__ float pooled[64];
    __shared__ float hid[32];
    for (int i = t; i < 192; i += 64) {
        const int h = i >> 5, dh = i & 31;
        float s = 0.f;
        #pragma unroll
        for (int sg = 0; sg < 8; ++sg)
            s += partial[(((size_t)(b * H_ + h)) * 8 + sg) * 32 + dh];
        cs[i] = s;
    }
    __syncthreads();
    float a = 0.f;
    for (int e = 0; e < 192; ++e) a = fmaf(cs[e], Wo[e * 64 + t], a);
    pooled[t] = a * (1.0f / (float)N_);
    __syncthreads();
    if (t < 32) {
        float s = bh1[t];
        for (int d = 0; d < 64; ++d) s = fmaf(pooled[d], Wh1[d * 32 + t], s);
        hid[t] = 0.5f * s * (1.0f + erff(s * 0.7071067811865476f));
    }
    __syncthreads();
    if (t < 7) {
        float s = bh2[t];
        for (int j = 0; j < 32; ++j) s = fmaf(hid[j], Wh2[j * 7 + t], s);
        out[b * 7 + t] = s;
    }
}

// ---------------------------------------------------------------------------
extern "C" void kernel_launch(void* const* d_in, const int* in_sizes, int n_in,
                              void* d_out, int out_size, void* d_ws, size_t ws_size,
                              hipStream_t stream)
{
    const float* x     = (const float*)d_in[0];
    const float* We    = (const float*)d_in[1];
    const float* be    = (const float*)d_in[2];
    const float* gamma = (const float*)d_in[3];
    const float* Wq    = (const float*)d_in[4];
    const float* Wk    = (const float*)d_in[5];
    const float* Wv    = (const float*)d_in[6];
    const float* kpos  = (const float*)d_in[7];
    const float* vpos  = (const float*)d_in[8];
    const float* mk    = (const float*)d_in[9];
    const float* mv    = (const float*)d_in[10];
    const float* Wkc1  = (const float*)d_in[11];
    const float* bkc1  = (const float*)d_in[12];
    const float* Wkc2  = (const float*)d_in[13];
    const float* bkc2  = (const float*)d_in[14];
    const float* Wvc1  = (const float*)d_in[15];
    const float* bvc1  = (const float*)d_in[16];
    const float* Wvc2  = (const float*)d_in[17];
    const float* bvc2  = (const float*)d_in[18];
    const float* Wg    = (const float*)d_in[19];
    const float* bg    = (const float*)d_in[20];
    const float* Wo    = (const float*)d_in[21];
    const float* Wh1   = (const float*)d_in[22];
    const float* bh1   = (const float*)d_in[23];
    const float* Wh2   = (const float*)d_in[24];
    const float* bh2   = (const float*)d_in[25];
    float* out = (float*)d_out;

    const int B = in_sizes[0] / N_;
    const int BH = B * H_;
    const int BHN = BH * N_;
    const size_t SZ = (size_t)BHN * DH_;

    float* ws   = (float*)d_ws;
    float* q_   = ws;
    float* qr_  = ws + SZ;
    float* kr_  = ws + 2 * SZ;
    float* v_   = ws + 3 * SZ;
    ushort_t* kin_hi = (ushort_t*)(ws + 4 * SZ);
    ushort_t* kin_lo = kin_hi + SZ;
    ushort_t* vin_hi = kin_hi + 2 * SZ;
    ushort_t* vin_lo = kin_hi + 3 * SZ;   // occupies ws[4SZ .. 6SZ)
    float* ck_  = ws + 6 * SZ;
    float* cv_  = ck_ + (size_t)BH * 33 * DH_;
    float* g_   = cv_ + (size_t)BH * 33 * DH_;
    float* partial_ = g_ + (size_t)BHN * 3;           // BH*8*32 floats
    ushort_t* wtk_hi = (ushort_t*)(partial_ + (size_t)BH * 8 * 32);
    ushort_t* wtk_lo = wtk_hi + 512 * 512;
    ushort_t* wtv_hi = wtk_hi + 2 * 512 * 512;
    ushort_t* wtv_lo = wtk_hi + 3 * 512 * 512;

    k_cvtW<<<dim3(8, 8, 2), dim3(256), 0, stream>>>(
        Wkc1, Wvc1, wtk_hi, wtk_lo, wtv_hi, wtv_lo);
    k_embed<<<dim3(B * N_ / 64), dim3(768), 0, stream>>>(
        x, We, be, gamma, Wq, Wk, Wv, kpos, vpos, Wg, bg,
        q_, qr_, kr_, v_, kin_hi, kin_lo, vin_hi, vin_lo, g_);
    k_compress<<<dim3(BH, 2), dim3(256), 0, stream>>>(
        kin_hi, kin_lo, vin_hi, vin_lo, wtk_hi, wtk_lo, wtv_hi, wtv_lo,
        bkc1, Wkc2, bkc2, bvc1, Wvc2, bvc2, mk, mv, ck_, cv_);
    k_attn<<<dim3(BHN / 64), dim3(256), 0, stream>>>(
        q_, qr_, kr_, v_, ck_, cv_, g_, partial_);
    k_head<<<dim3(B), dim3(64), 0, stream>>>(partial_, Wo, Wh1, bh1, Wh2, bh2, out);
}

// Round 14
// 147.517 us; speedup vs baseline: 1.1352x; 1.1352x over previous
//
#include <hip/hip_runtime.h>

typedef unsigned short ushort_t;
typedef __attribute__((ext_vector_type(8))) short bf16x8;
typedef __attribute__((ext_vector_type(4))) float f32x4;

// Model constants (fixed by the reference)
constexpr int N_   = 512;
constexpr int D_   = 64;
constexpr int H_   = 6;
constexpr int DH_  = 32;
constexpr int CB_  = 16;
constexpr int SB_  = 8;
constexpr int HD_  = H_ * DH_;   // 192
constexpr int CD_  = CB_ * DH_;  // 512
constexpr int nC_  = N_ / CB_;   // 32
constexpr int nF_  = N_ / SB_;   // 64
constexpr float SCALE_ = 0.17677669529663687f; // 32^-0.5
constexpr float NEG_ = -3.4e38f;

__device__ __forceinline__ ushort_t f2bf(float x) {
    unsigned u = __float_as_uint(x);
    unsigned r = u + 0x7FFFu + ((u >> 16) & 1u);   // RNE
    return (ushort_t)(r >> 16);
}

// Fragment-major address for a [rows][512] bf16 matrix consumed by
// mfma_f32_16x16x32_bf16 (wave fragment load = one coalesced 1KB read).
__device__ __forceinline__ size_t frag_addr(int row, int k) {
    return (size_t)(row >> 4) * 8192 + (size_t)(k >> 5) * 512
         + (size_t)((k >> 3) & 3) * 128 + (size_t)(row & 15) * 8 + (k & 7);
}

// ---------------------------------------------------------------------------
// K0: transpose + split Wkc1 / Wvc1 (512x512 f32, [k][j]) -> frag-major bf16
// hi/lo over [j][k]. grid (8,8,2) x 256 threads, 64x64 tiles via LDS.
// ---------------------------------------------------------------------------
__global__ __launch_bounds__(256) void k_cvtW(
    const float* __restrict__ Wk1, const float* __restrict__ Wv1,
    ushort_t* __restrict__ wtk_hi, ushort_t* __restrict__ wtk_lo,
    ushort_t* __restrict__ wtv_hi, ushort_t* __restrict__ wtv_lo)
{
    const float* W = blockIdx.z ? Wv1 : Wk1;
    ushort_t* ohi = blockIdx.z ? wtv_hi : wtk_hi;
    ushort_t* olo = blockIdx.z ? wtv_lo : wtk_lo;
    const int k0 = blockIdx.x * 64, j0 = blockIdx.y * 64;
    const int t = threadIdx.x;
    __shared__ float tile[64][65];
    #pragma unroll 4
    for (int i = 0; i < 16; ++i) {
        const int lin = t + i * 256;
        const int kk = lin >> 6, jj = lin & 63;
        tile[kk][jj] = W[(size_t)(k0 + kk) * 512 + j0 + jj];
    }
    __syncthreads();
    #pragma unroll 4
    for (int i = 0; i < 16; ++i) {
        const int lin = t + i * 256;
        const int jj = lin >> 6, kk = lin & 63;
        const float x = tile[kk][jj];
        const ushort_t h = f2bf(x);
        const float hf = __uint_as_float((unsigned)h << 16);
        const size_t fo = frag_addr(j0 + jj, k0 + kk);
        ohi[fo] = h;
        olo[fo] = f2bf(x - hf);
    }
}

// ---------------------------------------------------------------------------
// K1: embed + norm + Q/K/V/gate projections + RoPE; kin/vin emitted bf16 hi/lo
// in MFMA-fragment-major layout. 192 threads = 3 waves; wave wv owns output
// column group m=wv for 16 rows. dd-loop blocked by 4 with float4 LDS reads.
// ---------------------------------------------------------------------------
__global__ __launch_bounds__(192) void k_embed(
    const float* __restrict__ x, const float* __restrict__ We, const float* __restrict__ be,
    const float* __restrict__ gamma,
    const float* __restrict__ Wq, const float* __restrict__ Wk, const float* __restrict__ Wv,
    const float* __restrict__ kpos, const float* __restrict__ vpos,
    const float* __restrict__ Wg, const float* __restrict__ bg,
    float* __restrict__ q, float* __restrict__ qr, float* __restrict__ kr,
    float* __restrict__ v,
    ushort_t* __restrict__ kin_hi, ushort_t* __restrict__ kin_lo,
    ushort_t* __restrict__ vin_hi, ushort_t* __restrict__ vin_lo,
    float* __restrict__ g)
{
    const int t  = threadIdx.x;
    const int wv = t >> 6;        // 0..2 == m
    const int ln = t & 63;
    const int n00 = blockIdx.x * 16;
    const int b = n00 / N_;
    const int nbase = n00 % N_;

    __shared__ float hn[16][64];

    for (int r = wv; r < 16; r += 3) {
        const int n = nbase + r;
        float xv = x[b * N_ + n];
        float h = fmaf(xv, We[ln], be[ln]);
        float ss = h * h;
        #pragma unroll
        for (int off = 32; off; off >>= 1) ss += __shfl_down(ss, off);
        ss = __shfl(ss, 0);
        float sc = 8.0f / fmaxf(sqrtf(ss), 1e-12f);
        hn[r][ln] = h * sc * (gamma[ln] + 1.0f);
    }
    __syncthreads();

    const int e  = ln + (wv << 6);
    const int hh = e >> 5;
    const int dh = e & 31;
    float aq[16], ak[16], av[16];
    #pragma unroll
    for (int r = 0; r < 16; ++r) { aq[r] = 0.f; ak[r] = 0.f; av[r] = 0.f; }
    for (int dd = 0; dd < 64; dd += 4) {
        float wq4[4], wk4[4], wv4[4];
        #pragma unroll
        for (int u = 0; u < 4; ++u) {
            wq4[u] = Wq[(dd + u) * HD_ + e];
            wk4[u] = Wk[(dd + u) * HD_ + e];
            wv4[u] = Wv[(dd + u) * HD_ + e];
        }
        #pragma unroll
        for (int r = 0; r < 16; ++r) {
            const float4 hv = *(const float4*)&hn[r][dd];
            aq[r] = fmaf(hv.x, wq4[0], aq[r]);
            aq[r] = fmaf(hv.y, wq4[1], aq[r]);
            aq[r] = fmaf(hv.z, wq4[2], aq[r]);
            aq[r] = fmaf(hv.w, wq4[3], aq[r]);
            ak[r] = fmaf(hv.x, wk4[0], ak[r]);
            ak[r] = fmaf(hv.y, wk4[1], ak[r]);
            ak[r] = fmaf(hv.z, wk4[2], ak[r]);
            ak[r] = fmaf(hv.w, wk4[3], ak[r]);
            av[r] = fmaf(hv.x, wv4[0], av[r]);
            av[r] = fmaf(hv.y, wv4[1], av[r]);
            av[r] = fmaf(hv.z, wv4[2], av[r]);
            av[r] = fmaf(hv.w, wv4[3], av[r]);
        }
    }
    const float invf = exp2f((float)(dh & ~1) * -0.41524101186092029f);
    #pragma unroll
    for (int r = 0; r < 16; ++r) {
        const int n = nbase + r;
        const size_t o = ((size_t)(b * H_ + hh) * N_ + n) * DH_ + dh;
        q[o] = aq[r];
        v[o] = av[r];
        const int pix = (hh * CB_ + (n & (CB_ - 1))) * DH_ + dh;
        const float kinv = ak[r] + kpos[pix];
        const float vinv = av[r] + vpos[pix];
        {
            const int row = (b * H_ + hh) * nC_ + (n >> 4);
            const int k   = (n & 15) * 32 + dh;
            const size_t fo = frag_addr(row, k);
            const ushort_t kh = f2bf(kinv);
            kin_hi[fo] = kh;
            kin_lo[fo] = f2bf(kinv - __uint_as_float((unsigned)kh << 16));
            const ushort_t vh = f2bf(vinv);
            vin_hi[fo] = vh;
            vin_lo[fo] = f2bf(vinv - __uint_as_float((unsigned)vh << 16));
        }
        const float aqp = __shfl_xor(aq[r], 1);
        const float akp = __shfl_xor(ak[r], 1);
        float sA, cA;
        __sincosf((float)n * invf, &sA, &cA);
        float rq, rk;
        if (dh & 1) { rq = fmaf(aqp, sA, aq[r] * cA); rk = fmaf(akp, sA, ak[r] * cA); }
        else        { rq = fmaf(-aqp, sA, aq[r] * cA); rk = fmaf(-akp, sA, ak[r] * cA); }
        qr[o] = rq; kr[o] = rk;
    }

    if (ln < 18) {
        for (int r = wv; r < 16; r += 3) {
            const int n = nbase + r;
            float a = bg[ln];
            for (int dd = 0; dd < 64; ++dd) a = fmaf(hn[r][dd], Wg[dd * 18 + ln], a);
            const float gv = 1.0f / (1.0f + __expf(-a));
            g[((size_t)(b * H_ + ln / 3) * N_ + n) * 3 + (ln % 3)] = gv;
        }
    }
}

// ---------------------------------------------------------------------------
// K2: compression MLP via bf16x3 MFMA, fragment-major direct loads.
// Also writes the memory-token slot 0 (block == one bh).
// ---------------------------------------------------------------------------
__global__ __launch_bounds__(256) void k_compress(
    const ushort_t* __restrict__ kin_hi, const ushort_t* __restrict__ kin_lo,
    const ushort_t* __restrict__ vin_hi, const ushort_t* __restrict__ vin_lo,
    const ushort_t* __restrict__ wtk_hi, const ushort_t* __restrict__ wtk_lo,
    const ushort_t* __restrict__ wtv_hi, const ushort_t* __restrict__ wtv_lo,
    const float* __restrict__ bk1, const float* __restrict__ Wk2, const float* __restrict__ bk2,
    const float* __restrict__ bv1, const float* __restrict__ Wv2, const float* __restrict__ bv2,
    const float* __restrict__ mk, const float* __restrict__ mv,
    float* __restrict__ ck, float* __restrict__ cv)
{
    const bool isv = blockIdx.y != 0;
    const ushort_t* xhi = isv ? vin_hi : kin_hi;
    const ushort_t* xlo = isv ? vin_lo : kin_lo;
    const ushort_t* whi = isv ? wtv_hi : wtk_hi;
    const ushort_t* wlo = isv ? wtv_lo : wtk_lo;
    const float* b1 = isv ? bv1 : bk1;
    const float* W2 = isv ? Wv2 : Wk2;
    const float* b2 = isv ? bv2 : bk2;
    const float* mtok = isv ? mv : mk;
    float* outp = isv ? cv : ck;

    const int row0 = blockIdx.x * 32;     // block == bh (32 rows = nC)
    const int t = threadIdx.x;
    const int w = t >> 6, l = t & 63;
    const int lrow = l & 15, kg = l >> 4;
    const int n0w = w * 128;

    __shared__ float hid[32 * 512];       // 64 KB
    __shared__ float wred[4 * 16 * 32];   // 8 KB

    // memory token -> slot 0
    if (t < 32) {
        outp[(size_t)blockIdx.x * 33 * DH_ + t] = mtok[(blockIdx.x % H_) * DH_ + t];
    }

    f32x4 acc[2][8];
    #pragma unroll
    for (int nt = 0; nt < 8; ++nt) {
        const float bv_ = b1[n0w + nt * 16 + lrow];
        #pragma unroll
        for (int mt = 0; mt < 2; ++mt) {
            acc[mt][nt][0] = bv_; acc[mt][nt][1] = bv_;
            acc[mt][nt][2] = bv_; acc[mt][nt][3] = bv_;
        }
    }
    const ushort_t* Ah = xhi + (size_t)(row0 >> 4) * 8192;
    const ushort_t* Al = xlo + (size_t)(row0 >> 4) * 8192;
    const ushort_t* Bh = whi + (size_t)(n0w >> 4) * 8192;
    const ushort_t* Bl = wlo + (size_t)(n0w >> 4) * 8192;
    const int lofs = l * 8;

    for (int ks = 0; ks < 16; ++ks) {
        const int kb = ks * 512 + lofs;
        const bf16x8 ah0 = *(const bf16x8*)(Ah + kb);
        const bf16x8 ah1 = *(const bf16x8*)(Ah + 8192 + kb);
        const bf16x8 al0 = *(const bf16x8*)(Al + kb);
        const bf16x8 al1 = *(const bf16x8*)(Al + 8192 + kb);
        #pragma unroll
        for (int nt = 0; nt < 8; ++nt) {
            const bf16x8 bh = *(const bf16x8*)(Bh + nt * 8192 + kb);
            const bf16x8 bl = *(const bf16x8*)(Bl + nt * 8192 + kb);
            acc[0][nt] = __builtin_amdgcn_mfma_f32_16x16x32_bf16(ah0, bh, acc[0][nt], 0, 0, 0);
            acc[0][nt] = __builtin_amdgcn_mfma_f32_16x16x32_bf16(ah0, bl, acc[0][nt], 0, 0, 0);
            acc[0][nt] = __builtin_amdgcn_mfma_f32_16x16x32_bf16(al0, bh, acc[0][nt], 0, 0, 0);
            acc[1][nt] = __builtin_amdgcn_mfma_f32_16x16x32_bf16(ah1, bh, acc[1][nt], 0, 0, 0);
            acc[1][nt] = __builtin_amdgcn_mfma_f32_16x16x32_bf16(ah1, bl, acc[1][nt], 0, 0, 0);
            acc[1][nt] = __builtin_amdgcn_mfma_f32_16x16x32_bf16(al1, bh, acc[1][nt], 0, 0, 0);
        }
    }
    #pragma unroll
    for (int mt = 0; mt < 2; ++mt) {
        #pragma unroll
        for (int nt = 0; nt < 8; ++nt) {
            const int col = n0w + nt * 16 + lrow;
            #pragma unroll
            for (int r = 0; r < 4; ++r) {
                const int row = mt * 16 + kg * 4 + r;
                hid[row * 512 + col] = fmaxf(acc[mt][nt][r], 0.0f);
            }
        }
    }
    __syncthreads();

    const int o = t & 31, seg = t >> 5;
    for (int half = 0; half < 2; ++half) {
        const int r0 = half * 16;
        float s[16];
        #pragma unroll
        for (int r = 0; r < 16; ++r) s[r] = 0.f;
        for (int di = 0; di < 64; ++di) {
            const int dd = seg * 64 + di;
            const float w2 = W2[(size_t)dd * 32 + o];
            #pragma unroll
            for (int r = 0; r < 16; ++r) s[r] = fmaf(hid[(r0 + r) * 512 + dd], w2, s[r]);
        }
        #pragma unroll
        for (int r = 0; r < 16; ++r) s[r] += __shfl_xor(s[r], 32);
        if (l < 32) {
            #pragma unroll
            for (int r = 0; r < 16; ++r) wred[(w * 16 + r) * 32 + o] = s[r];
        }
        __syncthreads();
        {
            const int rr = t >> 5;   // 0..7
            #pragma unroll
            for (int u = 0; u < 2; ++u) {
                const int r = rr + u * 8;
                const float val = wred[r * 32 + o] + wred[(16 + r) * 32 + o]
                                + wred[(32 + r) * 32 + o] + wred[(48 + r) * 32 + o] + b2[o];
                const int grow = row0 + r0 + r;
                outp[((size_t)(grow >> 5) * 33 + 1 + (grow & 31)) * DH_ + o] = val;
            }
        }
        __syncthreads();
    }
}

// ---------------------------------------------------------------------------
// K3: fused attention + pooling partial. Quarter-wave per query; CONSECUTIVE
// n per block (L1 locality); epilogue reduces the block's 64 query outputs
// (mean-pool numerator) -> partial[bh*8+blk][32].
// ---------------------------------------------------------------------------
__global__ __launch_bounds__(256) void k_attn(
    const float* __restrict__ q, const float* __restrict__ qr,
    const float* __restrict__ kr, const float* __restrict__ v,
    const float* __restrict__ ck, const float* __restrict__ cv,
    const float* __restrict__ g, float* __restrict__ partial)
{
    const int t = threadIdx.x;
    const int sub = t & 3;
    const int wv = t >> 6;
    const int l = t & 63;
    const int bh = blockIdx.x >> 3;
    const int blk = blockIdx.x & 7;
    const int qi = t >> 2;                    // 0..63 consecutive
    const int n = blk * 64 + qi;
    const int qb = n >> 3;

    float qv[8];
    {
        const float4* p = (const float4*)(q + ((size_t)bh * N_ + n) * DH_ + sub * 8);
        const float4 f0 = p[0], f1 = p[1];
        qv[0]=f0.x; qv[1]=f0.y; qv[2]=f0.z; qv[3]=f0.w;
        qv[4]=f1.x; qv[5]=f1.y; qv[6]=f1.z; qv[7]=f1.w;
    }
    const float* ckb = ck + (size_t)bh * 33 * DH_;
    const float* cvb = cv + (size_t)bh * 33 * DH_;

    float mx = -INFINITY, den = 0.f;
    float cres[8];
    #pragma unroll
    for (int d = 0; d < 8; ++d) cres[d] = 0.f;
    float m2 = -1000.0f, sum2 = 1.0f;
    float v1 = -INFINITY, v2 = -INFINITY;
    int i1 = 0, i2 = 0;

    const int jend = 1 + max(n >> 4, (qb + 1) >> 1);
    for (int j = 0; j < jend; ++j) {
        float a = 0.f;
        {
            const float4* kp = (const float4*)(ckb + j * DH_ + sub * 8);
            const float4 f0 = kp[0], f1 = kp[1];
            a = fmaf(qv[0], f0.x, a); a = fmaf(qv[1], f0.y, a);
            a = fmaf(qv[2], f0.z, a); a = fmaf(qv[3], f0.w, a);
            a = fmaf(qv[4], f1.x, a); a = fmaf(qv[5], f1.y, a);
            a = fmaf(qv[6], f1.z, a); a = fmaf(qv[7], f1.w, a);
        }
        a += __shfl_xor(a, 1);
        a += __shfl_xor(a, 2);
        const bool ok = (j == 0) || (j * CB_ - 1 < n);
        a = ok ? a * SCALE_ : NEG_;

        float p;
        if (a > mx) {
            const float sc_ = __expf(mx - a);
            den *= sc_;
            #pragma unroll
            for (int d = 0; d < 8; ++d) cres[d] *= sc_;
            mx = a; p = 1.0f;
        } else {
            p = __expf(a - mx);
        }
        den += p;
        {
            const float4* vp = (const float4*)(cvb + j * DH_ + sub * 8);
            const float4 f0 = vp[0], f1 = vp[1];
            cres[0] = fmaf(p, f0.x, cres[0]); cres[1] = fmaf(p, f0.y, cres[1]);
            cres[2] = fmaf(p, f0.z, cres[2]); cres[3] = fmaf(p, f0.w, cres[3]);
            cres[4] = fmaf(p, f1.x, cres[4]); cres[5] = fmaf(p, f1.y, cres[5]);
            cres[6] = fmaf(p, f1.z, cres[6]); cres[7] = fmaf(p, f1.w, cres[7]);
        }

        if (j >= 1) {
            const int f0i = 2 * (j - 1);
            const int cnt = (qb > f0i) + (qb > f0i + 1);
            if (cnt) {
                if (a > m2) {
                    sum2 = fmaf(sum2, __expf(m2 - a), (float)cnt);
                    m2 = a;
                } else {
                    sum2 = fmaf((float)cnt, __expf(a - m2), sum2);
                }
                if (a > v1) {
                    if (cnt == 2) { v2 = a; i2 = f0i + 1; }
                    else          { v2 = v1; i2 = i1; }
                    v1 = a; i1 = f0i;
                } else if (a > v2) {
                    v2 = a; i2 = f0i;
                }
            }
        }
    }
    {
        const float invd = 1.0f / den;
        #pragma unroll
        for (int d = 0; d < 8; ++d) cres[d] *= invd;
    }
    const float isum = 1.0f / sum2;
    const bool bm0 = __expf(v1 - m2) * isum > 1e-10f;
    const bool bm1 = __expf(v2 - m2) * isum > 1e-10f;

    float qrv[8];
    {
        const float4* p = (const float4*)(qr + ((size_t)bh * N_ + n) * DH_ + sub * 8);
        const float4 f0 = p[0], f1 = p[1];
        qrv[0]=f0.x; qrv[1]=f0.y; qrv[2]=f0.z; qrv[3]=f0.w;
        qrv[4]=f1.x; qrv[5]=f1.y; qrv[6]=f1.z; qrv[7]=f1.w;
    }
    const float* krb = kr + (size_t)bh * N_ * DH_;
    const float* vb  = v  + (size_t)bh * N_ * DH_;

    int blocks[3]; bool bmask[3];
    blocks[0] = i1; blocks[1] = i2; blocks[2] = qb;
    bmask[0] = bm0; bmask[1] = bm1; bmask[2] = true;

    float fmx = -INFINITY, fden = 0.f;
    float fo[8];
    #pragma unroll
    for (int d = 0; d < 8; ++d) fo[d] = 0.f;
    #pragma unroll
    for (int s = 0; s < 3; ++s) {
        const int base = blocks[s] * SB_;
        #pragma unroll
        for (int j = 0; j < 8; ++j) {
            const int row = base + j;
            float a = 0.f;
            {
                const float4* kp = (const float4*)(krb + (size_t)row * DH_ + sub * 8);
                const float4 f0 = kp[0], f1 = kp[1];
                a = fmaf(qrv[0], f0.x, a); a = fmaf(qrv[1], f0.y, a);
                a = fmaf(qrv[2], f0.z, a); a = fmaf(qrv[3], f0.w, a);
                a = fmaf(qrv[4], f1.x, a); a = fmaf(qrv[5], f1.y, a);
                a = fmaf(qrv[6], f1.z, a); a = fmaf(qrv[7], f1.w, a);
            }
            a += __shfl_xor(a, 1);
            a += __shfl_xor(a, 2);
            const bool ok = (s < 2) ? bmask[s] : (j <= (n & 7));
            a = ok ? a * SCALE_ : NEG_;

            float p;
            if (a > fmx) {
                const float sc_ = __expf(fmx - a);
                fden *= sc_;
                #pragma unroll
                for (int d = 0; d < 8; ++d) fo[d] *= sc_;
                fmx = a; p = 1.0f;
            } else {
                p = __expf(a - fmx);
            }
            fden += p;
            const float4* vp = (const float4*)(vb + (size_t)row * DH_ + sub * 8);
            const float4 f0 = vp[0], f1 = vp[1];
            fo[0] = fmaf(p, f0.x, fo[0]); fo[1] = fmaf(p, f0.y, fo[1]);
            fo[2] = fmaf(p, f0.z, fo[2]); fo[3] = fmaf(p, f0.w, fo[3]);
            fo[4] = fmaf(p, f1.x, fo[4]); fo[5] = fmaf(p, f1.y, fo[5]);
            fo[6] = fmaf(p, f1.z, fo[6]); fo[7] = fmaf(p, f1.w, fo[7]);
        }
    }
    const float finv = 1.0f / fden;

    float wmx = -INFINITY, wden = 0.f;
    float so[8];
    #pragma unroll
    for (int d = 0; d < 8; ++d) so[d] = 0.f;
    #pragma unroll
    for (int w = 0; w < 8; ++w) {
        const int row = (n - w) >= 0 ? (n - w) : 0;
        float a;
        if (w <= n) {
            a = 0.f;
            const float4* kp = (const float4*)(krb + (size_t)row * DH_ + sub * 8);
            const float4 f0 = kp[0], f1 = kp[1];
            a = fmaf(qrv[0], f0.x, a); a = fmaf(qrv[1], f0.y, a);
            a = fmaf(qrv[2], f0.z, a); a = fmaf(qrv[3], f0.w, a);
            a = fmaf(qrv[4], f1.x, a); a = fmaf(qrv[5], f1.y, a);
            a = fmaf(qrv[6], f1.z, a); a = fmaf(qrv[7], f1.w, a);
            a += __shfl_xor(a, 1);
            a += __shfl_xor(a, 2);
            a *= SCALE_;
        } else a = NEG_;

        float p;
        if (a > wmx) {
            const float sc_ = __expf(wmx - a);
            wden *= sc_;
            #pragma unroll
            for (int d = 0; d < 8; ++d) so[d] *= sc_;
            wmx = a; p = 1.0f;
        } else {
            p = __expf(a - wmx);
        }
        wden += p;
        const float4* vp = (const float4*)(vb + (size_t)row * DH_ + sub * 8);
        const float4 f0 = vp[0], f1 = vp[1];
        so[0] = fmaf(p, f0.x, so[0]); so[1] = fmaf(p, f0.y, so[1]);
        so[2] = fmaf(p, f0.z, so[2]); so[3] = fmaf(p, f0.w, so[3]);
        so[4] = fmaf(p, f1.x, so[4]); so[5] = fmaf(p, f1.y, so[5]);
        so[6] = fmaf(p, f1.z, so[6]); so[7] = fmaf(p, f1.w, so[7]);
    }
    const float winv = 1.0f / wden;

    const float g0 = g[((size_t)bh * N_ + n) * 3];
    const float g1 = g[((size_t)bh * N_ + n) * 3 + 1];
    const float g2 = g[((size_t)bh * N_ + n) * 3 + 2];
    float o[8];
    #pragma unroll
    for (int d = 0; d < 8; ++d)
        o[d] = g0 * cres[d] + g1 * (fo[d] * finv) + g2 * (so[d] * winv);

    // ---- pooling partial: sum this block's 64 queries ----
    #pragma unroll
    for (int d = 0; d < 8; ++d) {
        o[d] += __shfl_down(o[d], 32);
        o[d] += __shfl_down(o[d], 16);
        o[d] += __shfl_down(o[d], 8);
        o[d] += __shfl_down(o[d], 4);
    }
    __shared__ float red[4][32];
    if (l < 4) {
        #pragma unroll
        for (int d = 0; d < 8; ++d) red[wv][l * 8 + d] = o[d];
    }
    __syncthreads();
    if (t < 32) {
        const float s = red[0][t] + red[1][t] + red[2][t] + red[3][t];
        partial[((size_t)bh * 8 + blk) * 32 + t] = s;
    }
}

// ---------------------------------------------------------------------------
// K5: pooled = (sum partials)@Wo/N ; gelu MLP head -> out (B,7)
// partial layout: [bh][8][32]
// ---------------------------------------------------------------------------
__global__ void k_head(const float* __restrict__ partial, const float* __restrict__ Wo,
                       const float* __restrict__ Wh1, const float* __restrict__ bh1,
                       const float* __restrict__ Wh2, const float* __restrict__ bh2,
                       float* __restrict__ out)
{
    const int b = blockIdx.x;
    const int t = threadIdx.x; // 64
    __shared__ float cs[192];
    __shared__ float pooled[64];
    __shared__ float hid[32];
    for (int i = t; i < 192; i += 64) {
        const int h = i >> 5, dh = i & 31;
        float s = 0.f;
        #pragma unroll
        for (int sg = 0; sg < 8; ++sg)
            s += partial[(((size_t)(b * H_ + h)) * 8 + sg) * 32 + dh];
        cs[i] = s;
    }
    __syncthreads();
    float a = 0.f;
    for (int e = 0; e < 192; ++e) a = fmaf(cs[e], Wo[e * 64 + t], a);
    pooled[t] = a * (1.0f / (float)N_);
    __syncthreads();
    if (t < 32) {
        float s = bh1[t];
        for (int d = 0; d < 64; ++d) s = fmaf(pooled[d], Wh1[d * 32 + t], s);
        hid[t] = 0.5f * s * (1.0f + erff(s * 0.7071067811865476f));
    }
    __syncthreads();
    if (t < 7) {
        float s = bh2[t];
        for (int j = 0; j < 32; ++j) s = fmaf(hid[j], Wh2[j * 7 + t], s);
        out[b * 7 + t] = s;
    }
}

// ---------------------------------------------------------------------------
extern "C" void kernel_launch(void* const* d_in, const int* in_sizes, int n_in,
                              void* d_out, int out_size, void* d_ws, size_t ws_size,
                              hipStream_t stream)
{
    const float* x     = (const float*)d_in[0];
    const float* We    = (const float*)d_in[1];
    const float* be    = (const float*)d_in[2];
    const float* gamma = (const float*)d_in[3];
    const float* Wq    = (const float*)d_in[4];
    const float* Wk    = (const float*)d_in[5];
    const float* Wv    = (const float*)d_in[6];
    const float* kpos  = (const float*)d_in[7];
    const float* vpos  = (const float*)d_in[8];
    const float* mk    = (const float*)d_in[9];
    const float* mv    = (const float*)d_in[10];
    const float* Wkc1  = (const float*)d_in[11];
    const float* bkc1  = (const float*)d_in[12];
    const float* Wkc2  = (const float*)d_in[13];
    const float* bkc2  = (const float*)d_in[14];
    const float* Wvc1  = (const float*)d_in[15];
    const float* bvc1  = (const float*)d_in[16];
    const float* Wvc2  = (const float*)d_in[17];
    const float* bvc2  = (const float*)d_in[18];
    const float* Wg    = (const float*)d_in[19];
    const float* bg    = (const float*)d_in[20];
    const float* Wo    = (const float*)d_in[21];
    const float* Wh1   = (const float*)d_in[22];
    const float* bh1   = (const float*)d_in[23];
    const float* Wh2   = (const float*)d_in[24];
    const float* bh2   = (const float*)d_in[25];
    float* out = (float*)d_out;

    const int B = in_sizes[0] / N_;
    const int BH = B * H_;
    const int BHN = BH * N_;
    const size_t SZ = (size_t)BHN * DH_;

    float* ws   = (float*)d_ws;
    float* q_   = ws;
    float* qr_  = ws + SZ;
    float* kr_  = ws + 2 * SZ;
    float* v_   = ws + 3 * SZ;
    ushort_t* kin_hi = (ushort_t*)(ws + 4 * SZ);
    ushort_t* kin_lo = kin_hi + SZ;
    ushort_t* vin_hi = kin_hi + 2 * SZ;
    ushort_t* vin_lo = kin_hi + 3 * SZ;   // occupies ws[4SZ .. 6SZ)
    float* ck_  = ws + 6 * SZ;
    float* cv_  = ck_ + (size_t)BH * 33 * DH_;
    float* g_   = cv_ + (size_t)BH * 33 * DH_;
    float* partial_ = g_ + (size_t)BHN * 3;           // BH*8*32 floats
    ushort_t* wtk_hi = (ushort_t*)(partial_ + (size_t)BH * 8 * 32);
    ushort_t* wtk_lo = wtk_hi + 512 * 512;
    ushort_t* wtv_hi = wtk_hi + 2 * 512 * 512;
    ushort_t* wtv_lo = wtk_hi + 3 * 512 * 512;

    k_cvtW<<<dim3(8, 8, 2), dim3(256), 0, stream>>>(
        Wkc1, Wvc1, wtk_hi, wtk_lo, wtv_hi, wtv_lo);
    k_embed<<<dim3(B * N_ / 16), dim3(192), 0, stream>>>(
        x, We, be, gamma, Wq, Wk, Wv, kpos, vpos, Wg, bg,
        q_, qr_, kr_, v_, kin_hi, kin_lo, vin_hi, vin_lo, g_);
    k_compress<<<dim3(BH, 2), dim3(256), 0, stream>>>(
        kin_hi, kin_lo, vin_hi, vin_lo, wtk_hi, wtk_lo, wtv_hi, wtv_lo,
        bkc1, Wkc2, bkc2, bvc1, Wvc2, bvc2, mk, mv, ck_, cv_);
    k_attn<<<dim3(BHN / 64), dim3(256), 0, stream>>>(
        q_, qr_, kr_, v_, ck_, cv_, g_, partial_);
    k_head<<<dim3(B), dim3(64), 0, stream>>>(partial_, Wo, Wh1, bh1, Wh2, bh2, out);
}